// Round 6
// baseline (186.618 us; speedup 1.0000x reference)
//
#include <hip/hip_runtime.h>

// PatchesCreate: images [B=64, H=384, W=384, C=3] f32 (NHWC) ->
// patches [B, 576, 768] f32, P=16, G=24.
//
// v7: MAX-OCCUPANCY wave-private half-tiles, one-shot grid, NT/NT.
//
// Evidence so far: four NT/NT schedules (direct, one-shot LDS, pipelined
// persistent LDS, barrier-free wave-private LDS) all ~57-65 us dispatch
// (~4 TB/s effective vs 36 us copy-model floor). Counters: VALUBusy 2.6%,
// HBM 2.5 TB/s, Occupancy 27% -> latency-bound, nothing saturated. Common
// knob: ~9.25 KB LDS per wave -> 16 waves/CU cap. In-flight math: 9.8 GB/s
// per CU x 375 ns = 3.7 KB outstanding = ~0.2 wave-bursts; waves idle in
// waitcnt-chained phases with no loads in flight and too few peers to cover.
//
// v7 halves the wave tile: a HALF-row-pair (rows 2p,2p+1, gx in [12h,12h+12))
// is self-contained: 2 contiguous 2304 B input runs, 12 aligned 384 B output
// runs, 4.6 KB LDS. 4 waves x 4.62 KB = 18.5 KB/block -> 8 blocks/CU
// -> 32 waves/CU (100% thread cap). One tile per wave, one-shot 6144 blocks
// (block churn = fresh load bursts), no barriers, no persistence.
// f2 (8 B) granularity: 576 f2/tile = exactly 9 per lane.

typedef float f2 __attribute__((ext_vector_type(2)));

constexpr int ROW2   = 576;               // f2 per image row
constexpr int IMG2   = 384 * ROW2;        // 221184 f2 per image (in == out)
constexpr int GY2    = 24 * 384;          // 9216 f2 per gy-slab of patches
constexpr int LSTR2  = 289;               // 288 + 1 f2 pad
constexpr int LWAVE2 = 2 * LSTR2;         // 578 f2 = 4624 B per wave
constexpr int BLOCK  = 256;
constexpr int NTILE  = 64 * 24 * 8 * 2;   // 24576 half-row-pair tiles
constexpr int GRIDN  = NTILE / 4;         // 6144 blocks, one tile per wave

__global__ __launch_bounds__(BLOCK, 8)
void patches_kernel(const f2* __restrict__ in, f2* __restrict__ out) {
    __shared__ f2 lds[4 * LWAVE2];        // 18,496 B -> 8 blocks/CU
    const int wv = threadIdx.x >> 6;
    const int l  = threadIdx.x & 63;
    f2* __restrict__ L = &lds[wv * LWAVE2];

    const int tau = blockIdx.x * 4 + wv;  // tile id
    const int h   = tau & 1;              // gx half: 0 or 1
    const int t1  = tau >> 1;
    const int p   = t1 & 7;               // row-pair within slab
    const int t2  = t1 >> 3;
    const int gy  = t2 % 24;
    const int b   = t2 / 24;

    // ---- load: 2 contiguous 2304 B runs (rows 2p, 2p+1; cols [288h,288h+288))
    const f2* ibase = in + b * IMG2 + (gy * 16 + 2 * p) * ROW2 + h * 288;
    f2 v[9];
#pragma unroll
    for (int j = 0; j < 9; ++j) {
        int i  = l + j * 64;              // 0..575
        int r  = (i >= 288) ? 1 : 0;      // local row
        int c2 = i - r * 288;             // 0..287
        v[j] = __builtin_nontemporal_load(ibase + r * ROW2 + c2);
    }

    // ---- stage in wave-private LDS (linear, padded)
#pragma unroll
    for (int j = 0; j < 9; ++j) {
        int i  = l + j * 64;
        int r  = (i >= 288) ? 1 : 0;
        int c2 = i - r * 288;
        L[r * LSTR2 + c2] = v[j];
    }

    // ---- gather in output order, NT stores: 12 runs of 384 B (64 B aligned)
    // out chunk (gx=12h+gxl, py=2p+py2) at f2 offset gx*384 + p*48 + py2*24.
    f2* obase = out + b * IMG2 + gy * GY2 + h * (12 * 384) + p * 48;
#pragma unroll
    for (int j = 0; j < 9; ++j) {
        int o   = l + j * 64;             // 0..575
        int gxl = o / 48;                 // 0..11
        int w   = o - gxl * 48;           // 0..47
        int py2 = (w >= 24) ? 1 : 0;
        int w2  = w - py2 * 24;           // 0..23
        f2 x = L[py2 * LSTR2 + gxl * 24 + w2];
        __builtin_nontemporal_store(x, obase + gxl * 384 + py2 * 24 + w2);
    }
}

extern "C" void kernel_launch(void* const* d_in, const int* in_sizes, int n_in,
                              void* d_out, int out_size, void* d_ws, size_t ws_size,
                              hipStream_t stream) {
    const f2* in  = (const f2*)d_in[0];
    f2*       out = (f2*)d_out;
    patches_kernel<<<GRIDN, BLOCK, 0, stream>>>(in, out);
}

// Round 7
// 185.639 us; speedup vs baseline: 1.0053x; 1.0053x over previous
//
#include <hip/hip_runtime.h>

// PatchesCreate: images [B=64, H=384, W=384, C=3] f32 (NHWC) ->
// patches [B, 576, 768] f32, P=16, G=24.
//
// v8 = v7 geometry with FULL-BYPASS loads: global_load_dwordx2 sc0 sc1 nt.
//
// Evidence: six structures (direct / one-shot LDS / pipelined persistent /
// barrier-free wave-private / max-occupancy one-shot) all = 57-65 us
// dispatch; the ONLY lever that moved anything was the load cache policy
// (NT loads beat plain loads by 10.5 us with stores held NT, despite plain
// getting 58 MB of L3 hits). TLP arithmetic rules out latency: 16-32
// waves/CU x 4.6-9 KB issued loads >> 11 KB/CU needed for 3 TB/s reads.
// => limiter is cache-path interference between the read stream and the
// concurrent 113 MB write stream. __builtin_nontemporal_load sets only
// `nt`; v8 issues loads with `sc0 sc1 nt` (maximal no-allocate/bypass) via
// inline asm to eliminate the remaining L1/L2/L3 allocation on reads.
// Stores remain builtin-NT (proven best). Everything else is v7-identical:
// one half-row-pair tile per wave, wave-private 4.6 KB LDS, 18.5 KB/block,
// 8 blocks/CU, one-shot 6144 blocks, no barriers.
//
// Asm discipline: loads are volatile (program-ordered among volatile asm),
// "=&v" early-clobber dests; one explicit s_waitcnt vmcnt(0) + sched_barrier
// before the ds_writes (compiler does not track asm loads in its waitcnt).

typedef float f2 __attribute__((ext_vector_type(2)));

constexpr int ROW2   = 576;               // f2 per image row
constexpr int IMG2   = 384 * ROW2;        // 221184 f2 per image (in == out)
constexpr int GY2    = 24 * 384;          // 9216 f2 per gy-slab of patches
constexpr int LSTR2  = 289;               // 288 + 1 f2 pad (v7-identical)
constexpr int LWAVE2 = 2 * LSTR2;         // 578 f2 = 4624 B per wave
constexpr int BLOCK  = 256;
constexpr int NTILE  = 64 * 24 * 8 * 2;   // 24576 half-row-pair tiles
constexpr int GRIDN  = NTILE / 4;         // 6144 blocks, one tile per wave

__global__ __launch_bounds__(BLOCK, 8)
void patches_kernel(const f2* __restrict__ in, f2* __restrict__ out) {
    __shared__ f2 lds[4 * LWAVE2];        // 18,496 B -> 8 blocks/CU
    const int wv = threadIdx.x >> 6;
    const int l  = threadIdx.x & 63;
    f2* __restrict__ L = &lds[wv * LWAVE2];

    const int tau = blockIdx.x * 4 + wv;  // tile id
    const int h   = tau & 1;              // gx half: 0 or 1
    const int t1  = tau >> 1;
    const int p   = t1 & 7;               // row-pair within slab
    const int t2  = t1 >> 3;
    const int gy  = t2 % 24;
    const int b   = t2 / 24;

    // ---- load: 2 contiguous 2304 B runs, full cache bypass (sc0 sc1 nt)
    const f2* ibase = in + b * IMG2 + (gy * 16 + 2 * p) * ROW2 + h * 288;
    f2 v[9];
#pragma unroll
    for (int j = 0; j < 9; ++j) {
        int i  = l + j * 64;              // 0..575
        int r  = (i >= 288) ? 1 : 0;      // local row
        int c2 = i - r * 288;             // 0..287
        const f2* a = ibase + r * ROW2 + c2;
        asm volatile("global_load_dwordx2 %0, %1, off sc0 sc1 nt"
                     : "=&v"(v[j]) : "v"(a));
    }
    asm volatile("s_waitcnt vmcnt(0)" ::: "memory");
    __builtin_amdgcn_sched_barrier(0);

    // ---- stage in wave-private LDS (linear, padded; v7-identical)
#pragma unroll
    for (int j = 0; j < 9; ++j) {
        int i  = l + j * 64;
        int r  = (i >= 288) ? 1 : 0;
        int c2 = i - r * 288;
        L[r * LSTR2 + c2] = v[j];
    }
    asm volatile("s_waitcnt lgkmcnt(0)" ::: "memory");
    __builtin_amdgcn_sched_barrier(0);

    // ---- gather in output order, NT stores: 12 runs of 384 B (64 B aligned)
    f2* obase = out + b * IMG2 + gy * GY2 + h * (12 * 384) + p * 48;
#pragma unroll
    for (int j = 0; j < 9; ++j) {
        int o   = l + j * 64;             // 0..575
        int gxl = o / 48;                 // 0..11
        int w   = o - gxl * 48;           // 0..47
        int py2 = (w >= 24) ? 1 : 0;
        int w2  = w - py2 * 24;           // 0..23
        f2 x = L[py2 * LSTR2 + gxl * 24 + w2];
        __builtin_nontemporal_store(x, obase + gxl * 384 + py2 * 24 + w2);
    }
}

extern "C" void kernel_launch(void* const* d_in, const int* in_sizes, int n_in,
                              void* d_out, int out_size, void* d_ws, size_t ws_size,
                              hipStream_t stream) {
    const f2* in  = (const f2*)d_in[0];
    f2*       out = (f2*)d_out;
    patches_kernel<<<GRIDN, BLOCK, 0, stream>>>(in, out);
}